// Round 1
// baseline (1018.559 us; speedup 1.0000x reference)
//
#include <hip/hip_runtime.h>

#define NN 100000
#define NE 1000000
#define IND 128
#define OUTD 64
#define KST 4

// ---------------- degree / norm kernels ----------------

__global__ void k_zero(int* __restrict__ cnt) {
    int i = blockIdx.x * 256 + threadIdx.x;
    if (i < NN) cnt[i] = 0;
}

__global__ void k_count(const int* __restrict__ dst, int* __restrict__ cnt) {
    int e = blockIdx.x * 256 + threadIdx.x;
    if (e < NE) atomicAdd(&cnt[dst[e]], 1);
}

__global__ void k_norm(const int* __restrict__ cnt, float* __restrict__ r,
                       float* __restrict__ inv) {
    int i = blockIdx.x * 256 + threadIdx.x;
    if (i < NN) {
        float d1 = (float)cnt[i] + 1.0f;
        r[i]   = rsqrtf(d1);
        inv[i] = 1.0f / d1;
    }
}

// ---------------- h0 = feat @ W^T + b ; hinit = h0 * inv ----------------
// One wave per node. W staged in LDS transposed [k][o] (2-way bank alias = free).
// Feature row held in 2 regs/lane, broadcast via readlane (SALU, keeps DS pipe free).

__global__ __launch_bounds__(256) void k_gemm(const float* __restrict__ feat,
                                              const float* __restrict__ W,
                                              const float* __restrict__ bias,
                                              const float* __restrict__ inv,
                                              float* __restrict__ h0,
                                              float* __restrict__ hinit) {
    __shared__ float Wl[IND * OUTD];  // [k][o], 32 KiB
    int t = threadIdx.x;
#pragma unroll
    for (int i = 0; i < (IND * OUTD) / 256; ++i) {
        int idx = t + i * 256;
        int o = idx >> 7;        // W is [OUTD][IND] row-major
        int k = idx & 127;
        Wl[k * OUTD + o] = W[idx];
    }
    __syncthreads();

    int lane = t & 63;
    int wv   = t >> 6;
    float bv = bias[lane];

    for (int n = blockIdx.x * 4 + wv; n < NN; n += gridDim.x * 4) {
        float f0 = feat[n * IND + lane];
        float f1 = feat[n * IND + 64 + lane];
        float acc = 0.0f;
#pragma unroll
        for (int k = 0; k < 64; ++k) {
            float fk = __int_as_float(__builtin_amdgcn_readlane(__float_as_int(f0), k));
            acc = fmaf(Wl[k * OUTD + lane], fk, acc);
        }
#pragma unroll
        for (int k = 0; k < 64; ++k) {
            float fk = __int_as_float(__builtin_amdgcn_readlane(__float_as_int(f1), k));
            acc = fmaf(Wl[(k + 64) * OUTD + lane], fk, acc);
        }
        float h = acc + bv;
        h0[n * OUTD + lane]    = h;
        hinit[n * OUTD + lane] = h * inv[n];
    }
}

// ---------------- per-step kernels ----------------
// out = 0.5*h + 0.5*hinit  (then edge kernel atomically adds 0.5*r_d*r_s*h[src])

__global__ void k_init(float* __restrict__ out, const float* __restrict__ h,
                       const float* __restrict__ hi) {
    int i = blockIdx.x * 256 + threadIdx.x;
    int idx = i * 4;
    if (idx < NN * OUTD) {
        float4 a = *(const float4*)(h + idx);
        float4 c = *(const float4*)(hi + idx);
        float4 o;
        o.x = 0.5f * (a.x + c.x);
        o.y = 0.5f * (a.y + c.y);
        o.z = 0.5f * (a.z + c.z);
        o.w = 0.5f * (a.w + c.w);
        *(float4*)(out + idx) = o;
    }
}

// one wave per edge; lane = channel
__global__ __launch_bounds__(256) void k_edge(float* __restrict__ out,
                                              const float* __restrict__ h,
                                              const float* __restrict__ r,
                                              const int* __restrict__ src,
                                              const int* __restrict__ dst) {
    int t = blockIdx.x * 256 + threadIdx.x;
    int e = t >> 6;
    if (e >= NE) return;
    int c = t & 63;
    int s = src[e];
    int d = dst[e];
    float scale = 0.5f * r[s] * r[d];
    atomicAdd(&out[d * OUTD + c], scale * h[s * OUTD + c]);
}

// ---------------- launch ----------------

extern "C" void kernel_launch(void* const* d_in, const int* in_sizes, int n_in,
                              void* d_out, int out_size, void* d_ws, size_t ws_size,
                              hipStream_t stream) {
    const float* feat = (const float*)d_in[0];
    const float* W    = (const float*)d_in[1];
    const float* bias = (const float*)d_in[2];
    const int*   src  = (const int*)d_in[3];
    const int*   dst  = (const int*)d_in[4];

    char* ws = (char*)d_ws;
    // layout (bytes): cnt[NN] int | r[NN] f32 | inv[NN] f32 | hA[NN*64] f32 | hinit[NN*64] f32
    int*   cnt   = (int*)ws;
    float* r     = (float*)(ws + 400000);
    float* inv   = (float*)(ws + 800000);
    float* hA    = (float*)(ws + 1200000);
    float* hinit = (float*)(ws + 26800000);
    float* h0    = (float*)d_out;

    k_zero <<<(NN + 255) / 256, 256, 0, stream>>>(cnt);
    k_count<<<(NE + 255) / 256, 256, 0, stream>>>(dst, cnt);
    k_norm <<<(NN + 255) / 256, 256, 0, stream>>>(cnt, r, inv);
    k_gemm <<<2048, 256, 0, stream>>>(feat, W, bias, inv, h0, hinit);

    for (int k = 0; k < KST; ++k) {
        float* hc = (k & 1) ? hA : h0;   // h0,h2 in d_out; h1,h3 in hA
        float* hn = (k & 1) ? h0 : hA;
        k_init<<<(NN * OUTD) / 4 / 256, 256, 0, stream>>>(hn, hc, hinit);
        k_edge<<<(NE * 64) / 256, 256, 0, stream>>>(hn, hc, r, src, dst);
    }
}

// Round 2
// 478.888 us; speedup vs baseline: 2.1269x; 2.1269x over previous
//
#include <hip/hip_runtime.h>

#define NN 100000
#define NE 1000000
#define IND 128
#define OUTD 64
#define KST 4
#define NBLK ((NN + 255) / 256)   // 391 scan blocks

// ---------------- degree / norm ----------------

__global__ void k_zero(int* __restrict__ cnt) {
    int i = blockIdx.x * 256 + threadIdx.x;
    if (i < NN) cnt[i] = 0;
}

__global__ void k_count(const int* __restrict__ dst, int* __restrict__ cnt) {
    int e = blockIdx.x * 256 + threadIdx.x;
    if (e < NE) atomicAdd(&cnt[dst[e]], 1);
}

__global__ void k_norm(const int* __restrict__ cnt, float* __restrict__ r,
                       float* __restrict__ inv) {
    int i = blockIdx.x * 256 + threadIdx.x;
    if (i < NN) {
        float d1 = (float)cnt[i] + 1.0f;
        r[i]   = rsqrtf(d1);
        inv[i] = 1.0f / d1;
    }
}

// ---------------- CSR build: scan + bucket ----------------

__global__ void k_scan1(const int* __restrict__ cnt, int* __restrict__ rowptr,
                        int* __restrict__ bsum) {
    __shared__ int sd[256];
    int t = threadIdx.x;
    int i = blockIdx.x * 256 + t;
    int v = (i < NN) ? cnt[i] : 0;
    sd[t] = v;
    __syncthreads();
#pragma unroll
    for (int off = 1; off < 256; off <<= 1) {
        int x = (t >= off) ? sd[t - off] : 0;
        __syncthreads();
        sd[t] += x;
        __syncthreads();
    }
    if (i < NN) rowptr[i] = sd[t] - v;     // exclusive within block
    if (t == 255) bsum[blockIdx.x] = sd[255];
}

__global__ void k_scan2(int* __restrict__ bsum, int* __restrict__ bscan) {
    __shared__ int sd[512];
    int t = threadIdx.x;
    int v = (t < NBLK) ? bsum[t] : 0;
    sd[t] = v;
    __syncthreads();
#pragma unroll
    for (int off = 1; off < 512; off <<= 1) {
        int x = (t >= off) ? sd[t - off] : 0;
        __syncthreads();
        sd[t] += x;
        __syncthreads();
    }
    bscan[t] = sd[t] - v;                  // exclusive block offsets
}

__global__ void k_scan3(int* __restrict__ rowptr, const int* __restrict__ bscan) {
    int i = blockIdx.x * 256 + threadIdx.x;
    if (i < NN) rowptr[i] += bscan[blockIdx.x];
    if (i == 0) rowptr[NN] = NE;
}

__global__ void k_bucket(const int* __restrict__ src, const int* __restrict__ dst,
                         const int* __restrict__ rowptr, int* __restrict__ fill,
                         int* __restrict__ colidx) {
    int e = blockIdx.x * 256 + threadIdx.x;
    if (e < NE) {
        int d = dst[e];
        int pos = atomicAdd(&fill[d], 1);
        colidx[rowptr[d] + pos] = src[e];
    }
}

// ---------------- h0 = feat @ W^T + b ; hinit = h0 * inv ----------------

__global__ __launch_bounds__(256) void k_gemm(const float* __restrict__ feat,
                                              const float* __restrict__ W,
                                              const float* __restrict__ bias,
                                              const float* __restrict__ inv,
                                              float* __restrict__ h0,
                                              float* __restrict__ hinit) {
    __shared__ float Wl[IND * OUTD];  // [k][o], 32 KiB
    int t = threadIdx.x;
#pragma unroll
    for (int i = 0; i < (IND * OUTD) / 256; ++i) {
        int idx = t + i * 256;
        int o = idx >> 7;        // W is [OUTD][IND] row-major
        int k = idx & 127;
        Wl[k * OUTD + o] = W[idx];
    }
    __syncthreads();

    int lane = t & 63;
    int wv   = t >> 6;
    float bv = bias[lane];

    for (int n = blockIdx.x * 4 + wv; n < NN; n += gridDim.x * 4) {
        float f0 = feat[n * IND + lane];
        float f1 = feat[n * IND + 64 + lane];
        float acc = 0.0f;
#pragma unroll
        for (int k = 0; k < 64; ++k) {
            float fk = __int_as_float(__builtin_amdgcn_readlane(__float_as_int(f0), k));
            acc = fmaf(Wl[k * OUTD + lane], fk, acc);
        }
#pragma unroll
        for (int k = 0; k < 64; ++k) {
            float fk = __int_as_float(__builtin_amdgcn_readlane(__float_as_int(f1), k));
            acc = fmaf(Wl[(k + 64) * OUTD + lane], fk, acc);
        }
        float h = acc + bv;
        h0[n * OUTD + lane]    = h;
        hinit[n * OUTD + lane] = h * inv[n];
    }
}

// ---------------- propagation step: gather-reduce, no atomics ----------------
// hn[v][c] = 0.5*r[v]*sum_{s in in(v)} r[s]*h[s][c] + 0.5*h[v][c] + 0.5*hinit[v][c]

__global__ __launch_bounds__(256) void k_gather(float* __restrict__ hn,
                                                const float* __restrict__ h,
                                                const float* __restrict__ hinit,
                                                const float* __restrict__ r,
                                                const int* __restrict__ rowptr,
                                                const int* __restrict__ colidx) {
    int t = blockIdx.x * 256 + threadIdx.x;
    int v = t >> 6;
    if (v >= NN) return;
    int c = t & 63;
    int beg = rowptr[v];
    int end = rowptr[v + 1];

    float acc0 = 0.0f, acc1 = 0.0f;
    int j = beg;
    for (; j + 1 < end; j += 2) {   // two independent chains for ILP
        int s0 = colidx[j];
        int s1 = colidx[j + 1];
        float r0 = r[s0];
        float r1 = r[s1];
        float v0 = h[s0 * OUTD + c];
        float v1 = h[s1 * OUTD + c];
        acc0 = fmaf(r0, v0, acc0);
        acc1 = fmaf(r1, v1, acc1);
    }
    if (j < end) {
        int s0 = colidx[j];
        acc0 = fmaf(r[s0], h[s0 * OUTD + c], acc0);
    }
    float acc = acc0 + acc1;
    hn[v * OUTD + c] = fmaf(0.5f * r[v], acc,
                            0.5f * (h[v * OUTD + c] + hinit[v * OUTD + c]));
}

// ---------------- launch ----------------

extern "C" void kernel_launch(void* const* d_in, const int* in_sizes, int n_in,
                              void* d_out, int out_size, void* d_ws, size_t ws_size,
                              hipStream_t stream) {
    const float* feat = (const float*)d_in[0];
    const float* W    = (const float*)d_in[1];
    const float* bias = (const float*)d_in[2];
    const int*   src  = (const int*)d_in[3];
    const int*   dst  = (const int*)d_in[4];

    char* ws = (char*)d_ws;
    // layout (bytes):
    int*   cnt    = (int*)(ws + 0);          // 400,000 (degrees; reused as fill)
    float* r      = (float*)(ws + 400000);   // 400,000
    float* inv    = (float*)(ws + 800000);   // 400,000
    int*   rowptr = (int*)(ws + 1200000);    // 400,016 (NN+1)
    int*   bsum   = (int*)(ws + 1600016);    // 2,048
    int*   bscan  = (int*)(ws + 1602064);    // 2,048
    int*   colidx = (int*)(ws + 1604112);    // 4,000,000
    float* hA     = (float*)(ws + 5604112);  // 25,600,000
    float* hinit  = (float*)(ws + 31204112); // 25,600,000  (total ~56.8 MB)
    float* h0     = (float*)d_out;

    // degrees + norms
    k_zero <<<NBLK, 256, 0, stream>>>(cnt);
    k_count<<<(NE + 255) / 256, 256, 0, stream>>>(dst, cnt);
    k_norm <<<NBLK, 256, 0, stream>>>(cnt, r, inv);

    // CSR build
    k_scan1<<<NBLK, 256, 0, stream>>>(cnt, rowptr, bsum);
    k_scan2<<<1, 512, 0, stream>>>(bsum, bscan);
    k_scan3<<<NBLK, 256, 0, stream>>>(rowptr, bscan);
    k_zero <<<NBLK, 256, 0, stream>>>(cnt);          // cnt -> fill
    k_bucket<<<(NE + 255) / 256, 256, 0, stream>>>(src, dst, rowptr, cnt, colidx);

    // h0, hinit
    k_gemm <<<2048, 256, 0, stream>>>(feat, W, bias, inv, h0, hinit);

    // K=4 propagation steps, ping-pong d_out <-> hA (ends in d_out)
    for (int k = 0; k < KST; ++k) {
        float* hc = (k & 1) ? hA : h0;
        float* hn = (k & 1) ? h0 : hA;
        k_gather<<<(NN * 64 + 255) / 256, 256, 0, stream>>>(hn, hc, hinit, r,
                                                            rowptr, colidx);
    }
}

// Round 3
// 378.193 us; speedup vs baseline: 2.6932x; 1.2663x over previous
//
#include <hip/hip_runtime.h>

#define NN 100000
#define NE 1000000
#define IND 128
#define OUTD 64
#define KST 4
#define NBLK ((NN + 255) / 256)   // 391

__device__ __forceinline__ float bf2f(unsigned short u) {
    return __uint_as_float(((unsigned int)u) << 16);
}
__device__ __forceinline__ unsigned short f2bf(float f) {  // RNE
    unsigned int x = __float_as_uint(f);
    return (unsigned short)((x + 0x7fffu + ((x >> 16) & 1u)) >> 16);
}

// ---------------- degree / norm ----------------

__global__ void k_zero(int* __restrict__ cnt) {
    int i = blockIdx.x * 256 + threadIdx.x;
    if (i < NN) cnt[i] = 0;
}

__global__ void k_count(const int* __restrict__ dst, int* __restrict__ cnt) {
    int e = blockIdx.x * 256 + threadIdx.x;
    if (e < NE) atomicAdd(&cnt[dst[e]], 1);
}

__global__ void k_norm(const int* __restrict__ cnt, float* __restrict__ r) {
    int i = blockIdx.x * 256 + threadIdx.x;
    if (i < NN) r[i] = rsqrtf((float)cnt[i] + 1.0f);
}

// ---------------- CSR build ----------------

__global__ void k_scan1(const int* __restrict__ cnt, int* __restrict__ rowptr,
                        int* __restrict__ bsum) {
    __shared__ int sd[256];
    int t = threadIdx.x;
    int i = blockIdx.x * 256 + t;
    int v = (i < NN) ? cnt[i] : 0;
    sd[t] = v;
    __syncthreads();
#pragma unroll
    for (int off = 1; off < 256; off <<= 1) {
        int x = (t >= off) ? sd[t - off] : 0;
        __syncthreads();
        sd[t] += x;
        __syncthreads();
    }
    if (i < NN) rowptr[i] = sd[t] - v;     // exclusive within block
    if (t == 255) bsum[blockIdx.x] = sd[255];
}

__global__ void k_scan2(int* __restrict__ bsum, int* __restrict__ bscan) {
    __shared__ int sd[512];
    int t = threadIdx.x;
    int v = (t < NBLK) ? bsum[t] : 0;
    sd[t] = v;
    __syncthreads();
#pragma unroll
    for (int off = 1; off < 512; off <<= 1) {
        int x = (t >= off) ? sd[t - off] : 0;
        __syncthreads();
        sd[t] += x;
        __syncthreads();
    }
    bscan[t] = sd[t] - v;
}

__global__ void k_scan3(int* __restrict__ rowptr, const int* __restrict__ bscan,
                        int* __restrict__ fill) {
    int i = blockIdx.x * 256 + threadIdx.x;
    if (i < NN) {
        int p = rowptr[i] + bscan[blockIdx.x];
        rowptr[i] = p;
        fill[i]   = p;          // bucket cursor starts at row base
    }
    if (i == 0) rowptr[NN] = NE;
}

__global__ void k_bucket(const int* __restrict__ src, const int* __restrict__ dst,
                         int* __restrict__ fill, int* __restrict__ colidx) {
    int e = blockIdx.x * 256 + threadIdx.x;
    if (e < NE) {
        int pos = atomicAdd(&fill[dst[e]], 1);
        colidx[pos] = src[e];
    }
}

// ---------------- h0 = feat @ W^T + b (register-resident W) ----------------
// lane = output channel o; lane holds W[o][0..127] in VGPRs (static unrolled).
// feat broadcast via readlane (SALU co-issues with the FMA stream).

template<bool W16>
__global__ __launch_bounds__(256) void k_gemm(const float* __restrict__ feat,
                                              const float* __restrict__ W,
                                              const float* __restrict__ bias,
                                              const float* __restrict__ r,
                                              float* __restrict__ h0,
                                              float* __restrict__ hinit,
                                              unsigned short* __restrict__ h016) {
    int t = threadIdx.x;
    int lane = t & 63;
    int wv   = t >> 6;
    float w[IND];
#pragma unroll
    for (int i = 0; i < IND / 4; ++i) {
        float4 x = ((const float4*)W)[lane * (IND / 4) + i];
        w[4 * i + 0] = x.x; w[4 * i + 1] = x.y;
        w[4 * i + 2] = x.z; w[4 * i + 3] = x.w;
    }
    float bv = bias[lane];

    for (int n = blockIdx.x * 4 + wv; n < NN; n += gridDim.x * 4) {
        float f0 = feat[n * IND + lane];
        float f1 = feat[n * IND + 64 + lane];
        float acc = bv;
#pragma unroll
        for (int k = 0; k < 64; ++k) {
            float fk = __int_as_float(__builtin_amdgcn_readlane(__float_as_int(f0), k));
            acc = fmaf(fk, w[k], acc);
        }
#pragma unroll
        for (int k = 0; k < 64; ++k) {
            float fk = __int_as_float(__builtin_amdgcn_readlane(__float_as_int(f1), k));
            acc = fmaf(fk, w[64 + k], acc);
        }
        float rv = r[n];
        h0[n * OUTD + lane]    = acc;
        hinit[n * OUTD + lane] = acc * rv * rv;   // inv(deg+1) == r*r
        if (W16) h016[n * OUTD + lane] = f2bf(acc);
    }
}

// ---------------- propagation: gather-reduce ----------------
// hn[v][c] = 0.5*r[v]*sum_s r[s]*h[s][c] + 0.5*(h[v][c] + hinit[v][c])
// Wave per node; colidx preloaded lane-cooperatively, broadcast via readlane.

template<bool USE16>
__global__ __launch_bounds__(256) void k_gather(float* __restrict__ hn,
                                                unsigned short* __restrict__ hn16,
                                                const float* __restrict__ h,
                                                const unsigned short* __restrict__ h16,
                                                const float* __restrict__ hinit,
                                                const float* __restrict__ r,
                                                const int* __restrict__ rowptr,
                                                const int* __restrict__ colidx) {
    int t = blockIdx.x * 256 + threadIdx.x;
    int v = t >> 6;
    if (v >= NN) return;
    int c = t & 63;
    int beg = rowptr[v];
    int end = rowptr[v + 1];
    int deg = end - beg;
    int myi = (c < deg) ? colidx[beg + c] : 0;   // lanes hold first 64 indices
    int m = deg < 64 ? deg : 64;

    float a0 = 0.f, a1 = 0.f, a2 = 0.f, a3 = 0.f;
    int k = 0;
    for (; k + 3 < m; k += 4) {
        int s0 = __builtin_amdgcn_readlane(myi, k);
        int s1 = __builtin_amdgcn_readlane(myi, k + 1);
        int s2 = __builtin_amdgcn_readlane(myi, k + 2);
        int s3 = __builtin_amdgcn_readlane(myi, k + 3);
        if (USE16) {
            a0 = fmaf(r[s0], bf2f(h16[(size_t)s0 * OUTD + c]), a0);
            a1 = fmaf(r[s1], bf2f(h16[(size_t)s1 * OUTD + c]), a1);
            a2 = fmaf(r[s2], bf2f(h16[(size_t)s2 * OUTD + c]), a2);
            a3 = fmaf(r[s3], bf2f(h16[(size_t)s3 * OUTD + c]), a3);
        } else {
            a0 = fmaf(r[s0], h[(size_t)s0 * OUTD + c], a0);
            a1 = fmaf(r[s1], h[(size_t)s1 * OUTD + c], a1);
            a2 = fmaf(r[s2], h[(size_t)s2 * OUTD + c], a2);
            a3 = fmaf(r[s3], h[(size_t)s3 * OUTD + c], a3);
        }
    }
    for (; k < m; ++k) {
        int s = __builtin_amdgcn_readlane(myi, k);
        if (USE16) a0 = fmaf(r[s], bf2f(h16[(size_t)s * OUTD + c]), a0);
        else       a0 = fmaf(r[s], h[(size_t)s * OUTD + c], a0);
    }
    for (int j = beg + 64; j < end; ++j) {       // deg > 64 (rare)
        int s = colidx[j];
        if (USE16) a1 = fmaf(r[s], bf2f(h16[(size_t)s * OUTD + c]), a1);
        else       a1 = fmaf(r[s], h[(size_t)s * OUTD + c], a1);
    }
    float acc = (a0 + a1) + (a2 + a3);
    float out = fmaf(0.5f * r[v], acc,
                     0.5f * (h[v * OUTD + c] + hinit[v * OUTD + c]));
    hn[v * OUTD + c] = out;
    if (USE16) hn16[v * OUTD + c] = f2bf(out);
}

// ---------------- launch ----------------

extern "C" void kernel_launch(void* const* d_in, const int* in_sizes, int n_in,
                              void* d_out, int out_size, void* d_ws, size_t ws_size,
                              hipStream_t stream) {
    const float* feat = (const float*)d_in[0];
    const float* W    = (const float*)d_in[1];
    const float* bias = (const float*)d_in[2];
    const int*   src  = (const int*)d_in[3];
    const int*   dst  = (const int*)d_in[4];

    char* ws = (char*)d_ws;
    int*            cnt    = (int*)(ws + 0);          //   400,000 (degrees -> bucket cursor)
    float*          rr     = (float*)(ws + 400000);   //   400,000
    int*            rowptr = (int*)(ws + 800000);     //   400,016
    int*            bsum   = (int*)(ws + 1200128);    //     2,048
    int*            bscan  = (int*)(ws + 1202176);    //     2,048
    int*            colidx = (int*)(ws + 1204224);    // 4,000,000
    float*          hA     = (float*)(ws + 5204224);  // 25,600,000
    float*          hinit  = (float*)(ws + 30804224); // 25,600,000
    unsigned short* h16A   = (unsigned short*)(ws + 56404224); // 12,800,000
    unsigned short* h16B   = (unsigned short*)(ws + 69204224); // 12,800,000
    const size_t need16 = 82004224;
    float* h0 = (float*)d_out;
    bool use16 = ws_size >= need16;

    k_zero <<<NBLK, 256, 0, stream>>>(cnt);
    k_count<<<(NE + 255) / 256, 256, 0, stream>>>(dst, cnt);
    k_norm <<<NBLK, 256, 0, stream>>>(cnt, rr);

    k_scan1<<<NBLK, 256, 0, stream>>>(cnt, rowptr, bsum);
    k_scan2<<<1, 512, 0, stream>>>(bsum, bscan);
    k_scan3<<<NBLK, 256, 0, stream>>>(rowptr, bscan, cnt);
    k_bucket<<<(NE + 255) / 256, 256, 0, stream>>>(src, dst, cnt, colidx);

    if (use16) {
        k_gemm<true><<<1024, 256, 0, stream>>>(feat, W, bias, rr, h0, hinit, h16A);
        unsigned short* b16[2] = { h16A, h16B };
        for (int k = 0; k < KST; ++k) {
            float* hc = (k & 1) ? hA : h0;
            float* hn = (k & 1) ? h0 : hA;
            k_gather<true><<<(NN * 64 + 255) / 256, 256, 0, stream>>>(
                hn, b16[(k & 1) ^ 1], hc, b16[k & 1], hinit, rr, rowptr, colidx);
        }
    } else {
        k_gemm<false><<<1024, 256, 0, stream>>>(feat, W, bias, rr, h0, hinit, nullptr);
        for (int k = 0; k < KST; ++k) {
            float* hc = (k & 1) ? hA : h0;
            float* hn = (k & 1) ? h0 : hA;
            k_gather<false><<<(NN * 64 + 255) / 256, 256, 0, stream>>>(
                hn, nullptr, hc, nullptr, hinit, rr, rowptr, colidx);
        }
    }
}

// Round 4
// 349.158 us; speedup vs baseline: 2.9172x; 1.0832x over previous
//
#include <hip/hip_runtime.h>

#define NN 100000
#define NE 1000000
#define IND 128
#define OUTD 64
#define KST 4
#define NBLK ((NN + 255) / 256)   // 391
#define GM 64                     // gemm node tile

__device__ __forceinline__ float bf2f(unsigned short u) {
    return __uint_as_float(((unsigned int)u) << 16);
}
__device__ __forceinline__ unsigned short f2bf(float f) {  // RNE
    unsigned int x = __float_as_uint(f);
    return (unsigned short)((x + 0x7fffu + ((x >> 16) & 1u)) >> 16);
}

// ---------------- degree / norm ----------------

__global__ void k_zero(int* __restrict__ cnt) {
    int i = blockIdx.x * 256 + threadIdx.x;
    if (i < NN) cnt[i] = 0;
}

__global__ void k_count(const int* __restrict__ dst, int* __restrict__ cnt) {
    int e = blockIdx.x * 256 + threadIdx.x;
    if (e < NE) atomicAdd(&cnt[dst[e]], 1);
}

__global__ void k_norm(const int* __restrict__ cnt, float* __restrict__ r) {
    int i = blockIdx.x * 256 + threadIdx.x;
    if (i < NN) r[i] = rsqrtf((float)cnt[i] + 1.0f);
}

// ---------------- CSR build ----------------

__global__ void k_scan1(const int* __restrict__ cnt, int* __restrict__ rowptr,
                        int* __restrict__ bsum) {
    __shared__ int sd[256];
    int t = threadIdx.x;
    int i = blockIdx.x * 256 + t;
    int v = (i < NN) ? cnt[i] : 0;
    sd[t] = v;
    __syncthreads();
#pragma unroll
    for (int off = 1; off < 256; off <<= 1) {
        int x = (t >= off) ? sd[t - off] : 0;
        __syncthreads();
        sd[t] += x;
        __syncthreads();
    }
    if (i < NN) rowptr[i] = sd[t] - v;     // exclusive within block
    if (t == 255) bsum[blockIdx.x] = sd[255];
}

__global__ void k_scan2(int* __restrict__ bsum, int* __restrict__ bscan) {
    __shared__ int sd[512];
    int t = threadIdx.x;
    int v = (t < NBLK) ? bsum[t] : 0;
    sd[t] = v;
    __syncthreads();
#pragma unroll
    for (int off = 1; off < 512; off <<= 1) {
        int x = (t >= off) ? sd[t - off] : 0;
        __syncthreads();
        sd[t] += x;
        __syncthreads();
    }
    bscan[t] = sd[t] - v;
}

__global__ void k_scan3(int* __restrict__ rowptr, const int* __restrict__ bscan,
                        int* __restrict__ fill) {
    int i = blockIdx.x * 256 + threadIdx.x;
    if (i < NN) {
        int p = rowptr[i] + bscan[blockIdx.x];
        rowptr[i] = p;
        fill[i]   = p;          // bucket cursor starts at row base
    }
    if (i == 0) rowptr[NN] = NE;
}

__global__ void k_bucket(const int* __restrict__ src, const int* __restrict__ dst,
                         int* __restrict__ fill, int* __restrict__ colidx) {
    int e = blockIdx.x * 256 + threadIdx.x;
    if (e < NE) {
        int pos = atomicAdd(&fill[dst[e]], 1);
        colidx[pos] = src[e];
    }
}

// ---------------- tiled GEMM: h0 = feat @ W^T + b ----------------
// 64-node tile, 16x16 thread grid, 4x4 register tile per thread.
// Fl stride 132 (aligned float4 staging, conflict-free reads),
// Wl stride 129 (b32 staging, conflict-free reads).

template<bool W16>
__global__ __launch_bounds__(256) void k_gemm(const float* __restrict__ feat,
                                              const float* __restrict__ W,
                                              const float* __restrict__ bias,
                                              const float* __restrict__ r,
                                              float* __restrict__ h0,
                                              float* __restrict__ hinit,
                                              unsigned short* __restrict__ g16) {
    __shared__ float Fl[GM * (IND + 4)];     // 33,792 B
    __shared__ float Wl[OUTD * (IND + 1)];   // 33,024 B
    int t = threadIdx.x;

    // stage W: 2048 float4
#pragma unroll
    for (int i = 0; i < 8; ++i) {
        int idx = t + i * 256;
        int o  = idx >> 5;
        int k4 = idx & 31;
        float4 x = ((const float4*)W)[idx];
        float* dp = &Wl[o * (IND + 1) + k4 * 4];
        dp[0] = x.x; dp[1] = x.y; dp[2] = x.z; dp[3] = x.w;
    }
    // stage feat tile: 2048 float4
    int n0 = blockIdx.x * GM;
#pragma unroll
    for (int i = 0; i < 8; ++i) {
        int idx = t + i * 256;
        int nn = idx >> 5;
        int k4 = idx & 31;
        int n = n0 + nn;
        float4 x;
        if (n < NN) x = ((const float4*)feat)[n * 32 + k4];
        else        x = make_float4(0.f, 0.f, 0.f, 0.f);
        *(float4*)&Fl[nn * (IND + 4) + k4 * 4] = x;   // 528-byte stride, 16B-aligned
    }
    __syncthreads();

    int tx = t & 15;   // channel group: channels 4*tx..4*tx+3
    int ty = t >> 4;   // node group:    nodes   4*ty..4*ty+3
    float acc[4][4];
#pragma unroll
    for (int j = 0; j < 4; ++j)
#pragma unroll
        for (int i = 0; i < 4; ++i) acc[j][i] = 0.f;

    const float* fb = &Fl[(ty * 4) * (IND + 4)];
    const float* wb = &Wl[(tx * 4) * (IND + 1)];
#pragma unroll 8
    for (int k = 0; k < IND; ++k) {
        float a0 = fb[0 * (IND + 4) + k];
        float a1 = fb[1 * (IND + 4) + k];
        float a2 = fb[2 * (IND + 4) + k];
        float a3 = fb[3 * (IND + 4) + k];
        float b0 = wb[0 * (IND + 1) + k];
        float b1 = wb[1 * (IND + 1) + k];
        float b2 = wb[2 * (IND + 1) + k];
        float b3 = wb[3 * (IND + 1) + k];
        acc[0][0] = fmaf(a0, b0, acc[0][0]);
        acc[0][1] = fmaf(a0, b1, acc[0][1]);
        acc[0][2] = fmaf(a0, b2, acc[0][2]);
        acc[0][3] = fmaf(a0, b3, acc[0][3]);
        acc[1][0] = fmaf(a1, b0, acc[1][0]);
        acc[1][1] = fmaf(a1, b1, acc[1][1]);
        acc[1][2] = fmaf(a1, b2, acc[1][2]);
        acc[1][3] = fmaf(a1, b3, acc[1][3]);
        acc[2][0] = fmaf(a2, b0, acc[2][0]);
        acc[2][1] = fmaf(a2, b1, acc[2][1]);
        acc[2][2] = fmaf(a2, b2, acc[2][2]);
        acc[2][3] = fmaf(a2, b3, acc[2][3]);
        acc[3][0] = fmaf(a3, b0, acc[3][0]);
        acc[3][1] = fmaf(a3, b1, acc[3][1]);
        acc[3][2] = fmaf(a3, b2, acc[3][2]);
        acc[3][3] = fmaf(a3, b3, acc[3][3]);
    }

    float4 bv = ((const float4*)bias)[tx];
#pragma unroll
    for (int j = 0; j < 4; ++j) {
        int n = n0 + ty * 4 + j;
        if (n < NN) {
            float o0 = acc[j][0] + bv.x;
            float o1 = acc[j][1] + bv.y;
            float o2 = acc[j][2] + bv.z;
            float o3 = acc[j][3] + bv.w;
            float rv = r[n];
            float4 hh = make_float4(o0, o1, o2, o3);
            ((float4*)h0)[n * 16 + tx] = hh;
            float s = rv * rv;
            ((float4*)hinit)[n * 16 + tx] = make_float4(o0 * s, o1 * s, o2 * s, o3 * s);
            if (W16) {
                uint2 p;
                p.x = (unsigned int)f2bf(o0 * rv) | ((unsigned int)f2bf(o1 * rv) << 16);
                p.y = (unsigned int)f2bf(o2 * rv) | ((unsigned int)f2bf(o3 * rv) << 16);
                ((uint2*)g16)[n * 16 + tx] = p;
            }
        }
    }
}

// ---------------- propagation: gather-reduce ----------------
// g16[s][c] holds bf16(h[s][c] * r[s])  ->  inner loop is a pure add.
// hn[v][c] = 0.5*r[v]*sum_s g[s][c] + 0.5*(h[v][c] + hinit[v][c])

template<bool USE16>
__global__ __launch_bounds__(256) void k_gather(float* __restrict__ hn,
                                                unsigned short* __restrict__ gn16,
                                                const float* __restrict__ h,
                                                const unsigned short* __restrict__ g16,
                                                const float* __restrict__ hinit,
                                                const float* __restrict__ r,
                                                const int* __restrict__ rowptr,
                                                const int* __restrict__ colidx) {
    int t = blockIdx.x * 256 + threadIdx.x;
    int v = t >> 6;
    if (v >= NN) return;
    int c = t & 63;
    int beg = rowptr[v];
    int end = rowptr[v + 1];
    int deg = end - beg;
    int myi = (c < deg) ? colidx[beg + c] : 0;
    int m = deg < 64 ? deg : 64;

    float a0 = 0.f, a1 = 0.f, a2 = 0.f, a3 = 0.f;
    int k = 0;
    for (; k + 3 < m; k += 4) {
        int s0 = __builtin_amdgcn_readlane(myi, k);
        int s1 = __builtin_amdgcn_readlane(myi, k + 1);
        int s2 = __builtin_amdgcn_readlane(myi, k + 2);
        int s3 = __builtin_amdgcn_readlane(myi, k + 3);
        if (USE16) {
            a0 += bf2f(g16[(size_t)s0 * OUTD + c]);
            a1 += bf2f(g16[(size_t)s1 * OUTD + c]);
            a2 += bf2f(g16[(size_t)s2 * OUTD + c]);
            a3 += bf2f(g16[(size_t)s3 * OUTD + c]);
        } else {
            a0 = fmaf(r[s0], h[(size_t)s0 * OUTD + c], a0);
            a1 = fmaf(r[s1], h[(size_t)s1 * OUTD + c], a1);
            a2 = fmaf(r[s2], h[(size_t)s2 * OUTD + c], a2);
            a3 = fmaf(r[s3], h[(size_t)s3 * OUTD + c], a3);
        }
    }
    for (; k < m; ++k) {
        int s = __builtin_amdgcn_readlane(myi, k);
        if (USE16) a0 += bf2f(g16[(size_t)s * OUTD + c]);
        else       a0 = fmaf(r[s], h[(size_t)s * OUTD + c], a0);
    }
    for (int j = beg + 64; j < end; ++j) {       // deg > 64 (rare)
        int s = colidx[j];
        if (USE16) a1 += bf2f(g16[(size_t)s * OUTD + c]);
        else       a1 = fmaf(r[s], h[(size_t)s * OUTD + c], a1);
    }
    float acc = (a0 + a1) + (a2 + a3);
    float rv = r[v];
    float out = fmaf(0.5f * rv, acc,
                     0.5f * (h[v * OUTD + c] + hinit[v * OUTD + c]));
    hn[v * OUTD + c] = out;
    if (USE16) gn16[v * OUTD + c] = f2bf(out * rv);
}

// ---------------- launch ----------------

extern "C" void kernel_launch(void* const* d_in, const int* in_sizes, int n_in,
                              void* d_out, int out_size, void* d_ws, size_t ws_size,
                              hipStream_t stream) {
    const float* feat = (const float*)d_in[0];
    const float* W    = (const float*)d_in[1];
    const float* bias = (const float*)d_in[2];
    const int*   src  = (const int*)d_in[3];
    const int*   dst  = (const int*)d_in[4];

    char* ws = (char*)d_ws;
    int*            cnt    = (int*)(ws + 0);          //   400,000
    float*          rr     = (float*)(ws + 400000);   //   400,000
    int*            rowptr = (int*)(ws + 800000);     //   400,016
    int*            bsum   = (int*)(ws + 1200128);    //     2,048
    int*            bscan  = (int*)(ws + 1202176);    //     2,048
    int*            colidx = (int*)(ws + 1204224);    // 4,000,000
    float*          hA     = (float*)(ws + 5204224);  // 25,600,000
    float*          hinit  = (float*)(ws + 30804224); // 25,600,000
    unsigned short* g16A   = (unsigned short*)(ws + 56404224); // 12,800,000
    unsigned short* g16B   = (unsigned short*)(ws + 69204224); // 12,800,000
    const size_t need16 = 82004224;
    float* h0 = (float*)d_out;
    bool use16 = ws_size >= need16;

    k_zero <<<NBLK, 256, 0, stream>>>(cnt);
    k_count<<<(NE + 255) / 256, 256, 0, stream>>>(dst, cnt);
    k_norm <<<NBLK, 256, 0, stream>>>(cnt, rr);

    k_scan1<<<NBLK, 256, 0, stream>>>(cnt, rowptr, bsum);
    k_scan2<<<1, 512, 0, stream>>>(bsum, bscan);
    k_scan3<<<NBLK, 256, 0, stream>>>(rowptr, bscan, cnt);
    k_bucket<<<(NE + 255) / 256, 256, 0, stream>>>(src, dst, cnt, colidx);

    int gemm_blocks = (NN + GM - 1) / GM;   // 1563
    if (use16) {
        k_gemm<true><<<gemm_blocks, 256, 0, stream>>>(feat, W, bias, rr, h0, hinit, g16A);
        unsigned short* b16[2] = { g16A, g16B };
        for (int k = 0; k < KST; ++k) {
            float* hc = (k & 1) ? hA : h0;
            float* hn = (k & 1) ? h0 : hA;
            k_gather<true><<<(NN * 64 + 255) / 256, 256, 0, stream>>>(
                hn, b16[(k & 1) ^ 1], hc, b16[k & 1], hinit, rr, rowptr, colidx);
        }
    } else {
        k_gemm<false><<<gemm_blocks, 256, 0, stream>>>(feat, W, bias, rr, h0, hinit, nullptr);
        for (int k = 0; k < KST; ++k) {
            float* hc = (k & 1) ? hA : h0;
            float* hn = (k & 1) ? h0 : hA;
            k_gather<false><<<(NN * 64 + 255) / 256, 256, 0, stream>>>(
                hn, nullptr, hc, nullptr, hinit, rr, rowptr, colidx);
        }
    }
}